// Round 2
// baseline (3644.849 us; speedup 1.0000x reference)
//
#include <hip/hip_runtime.h>
#include <cstddef>

#define NN 50000
#define FF 16
#define TT 12
#define HH 128
#define EE 800000
#define OO 16

// ---------------- degree / normalization ----------------
__global__ void k_deg(const int* __restrict__ ei, const float* __restrict__ ew,
                      float* __restrict__ deg) {
  int e = blockIdx.x * 256 + threadIdx.x;
  if (e < EE) atomicAdd(&deg[ei[EE + e]], ew[e]);
}

__global__ void k_dinv(float* __restrict__ deg) {
  int n = blockIdx.x * 256 + threadIdx.x;
  if (n < NN) deg[n] = rsqrtf(deg[n] + 1.0f);  // self-loop weight 1 included
}

// Y[t][n][f] = dinv[n]^2 * x[n][f][t]   (self-loop term; full overwrite of Y)
__global__ void k_inity(const float* __restrict__ x, const float* __restrict__ dinv,
                        float* __restrict__ Y) {
  int tid = blockIdx.x * 256 + threadIdx.x;  // t*(N*4) + n*4 + f4
  if (tid >= TT * NN * 4) return;
  int t = tid / (NN * 4);
  int rem = tid - t * (NN * 4);
  int n = rem >> 2, f4 = rem & 3;
  float dv = dinv[n];
  dv *= dv;
  const float* xr = x + (size_t)n * (FF * TT);
  float4 v;
  v.x = dv * xr[(f4 * 4 + 0) * TT + t];
  v.y = dv * xr[(f4 * 4 + 1) * TT + t];
  v.z = dv * xr[(f4 * 4 + 2) * TT + t];
  v.w = dv * xr[(f4 * 4 + 3) * TT + t];
  *(float4*)&Y[((size_t)t * NN + n) * 16 + f4 * 4] = v;
}

// one wave per edge: lane covers 3 of the 192 columns (coalesced x reads)
__global__ void k_edges(const int* __restrict__ ei, const float* __restrict__ ew,
                        const float* __restrict__ dinv, const float* __restrict__ x,
                        float* __restrict__ Y) {
  long long gt = (long long)blockIdx.x * 256 + threadIdx.x;
  int wid = (int)(gt >> 6);
  if (wid >= EE) return;
  int lane = threadIdx.x & 63;
  int s = ei[wid], d = ei[EE + wid];
  float nrm = dinv[s] * ew[wid] * dinv[d];
  const float* xr = x + (size_t)s * (FF * TT);
#pragma unroll
  for (int i = 0; i < 3; i++) {
    int c = lane + 64 * i;        // c = f*12 + t
    int t = c % TT, f = c / TT;
    atomicAdd(&Y[((size_t)t * NN + d) * 16 + f], nrm * xr[c]);
  }
}

// ---------------- fused weight prep: A = conv_w @ lin_top, bfv = conv_b @ lin_top + lin_b
__global__ void k_prep(const float* __restrict__ czw, const float* __restrict__ czb,
                       const float* __restrict__ lzw, const float* __restrict__ lzb,
                       const float* __restrict__ crw, const float* __restrict__ crb,
                       const float* __restrict__ lrw, const float* __restrict__ lrb,
                       const float* __restrict__ chw, const float* __restrict__ chb,
                       const float* __restrict__ lhw, const float* __restrict__ lhb,
                       float* __restrict__ A, float* __restrict__ bfv) {
  const float *cw, *cb, *lw, *lb;
  if (blockIdx.x == 0)      { cw = czw; cb = czb; lw = lzw; lb = lzb; }
  else if (blockIdx.x == 1) { cw = crw; cb = crb; lw = lrw; lb = lrb; }
  else                      { cw = chw; cb = chb; lw = lhw; lb = lhb; }
  float* Ao = A + blockIdx.x * 2048;
  float* bo = bfv + blockIdx.x * 128;
  for (int idx = threadIdx.x; idx < 2048; idx += 256) {
    int f = idx >> 7, j = idx & 127;
    float acc = 0.f;
    for (int k = 0; k < 128; k++) acc = fmaf(cw[f * 128 + k], lw[k * 128 + j], acc);
    Ao[idx] = acc;
  }
  for (int j = threadIdx.x; j < 128; j += 256) {
    float acc = lb[j];
    for (int k = 0; k < 128; k++) acc = fmaf(cb[k], lw[k * 128 + j], acc);
    bo[j] = acc;
  }
}

// ---------------- main fused GRU + attention + output ----------------
// Thread (cg = tid&15, rg = tid>>4) owns rows rg*4..rg*4+3 and cols
// {cg*4..cg*4+3} u {64+cg*4..64+cg*4+3}.  acc[i][0..3] <-> cA+j,
// acc[i][4..7] <-> cB+j.  Weight reads are 16 lanes x 16B contiguous
// (256B span -> 2-way bank aliasing = free).

__device__ __forceinline__ void stage2048(float* wl, const float* __restrict__ g, int tid) {
  float4* d4 = (float4*)wl;
  const float4* s4 = (const float4*)g;
  d4[tid] = s4[tid];
  d4[tid + 256] = s4[tid + 256];
}

__device__ __forceinline__ void mm_chunk16(float acc[4][8], const float* src, int stride,
                                           int kbase, const float (*w)[128],
                                           int rg, int cA, int cB) {
#pragma unroll
  for (int kq = 0; kq < 4; kq++) {
    float s_[4][4];
#pragma unroll
    for (int i = 0; i < 4; i++) {
      float4 v = *(const float4*)&src[(rg * 4 + i) * stride + kbase + kq * 4];
      s_[i][0] = v.x; s_[i][1] = v.y; s_[i][2] = v.z; s_[i][3] = v.w;
    }
#pragma unroll
    for (int kk = 0; kk < 4; kk++) {
      const int k = kq * 4 + kk;
      float4 wa = *(const float4*)&w[k][cA];
      float4 wb = *(const float4*)&w[k][cB];
#pragma unroll
      for (int i = 0; i < 4; i++) {
        float hv = s_[i][kk];
        acc[i][0] = fmaf(hv, wa.x, acc[i][0]);
        acc[i][1] = fmaf(hv, wa.y, acc[i][1]);
        acc[i][2] = fmaf(hv, wa.z, acc[i][2]);
        acc[i][3] = fmaf(hv, wa.w, acc[i][3]);
        acc[i][4] = fmaf(hv, wb.x, acc[i][4]);
        acc[i][5] = fmaf(hv, wb.y, acc[i][5]);
        acc[i][6] = fmaf(hv, wb.z, acc[i][6]);
        acc[i][7] = fmaf(hv, wb.w, acc[i][7]);
      }
    }
  }
}

__device__ __forceinline__ void mm16(float acc[4][8], const float* ysrc,
                                     const float* __restrict__ Af, float (*w)[128],
                                     int rg, int cA, int cB, int tid) {
  stage2048(&w[0][0], Af, tid);
  __syncthreads();
  mm_chunk16(acc, ysrc, 20, 0, w, rg, cA, cB);
  __syncthreads();
}

__device__ __forceinline__ void mm128(float acc[4][8], const float* src, int stride,
                                      const float* __restrict__ B, float (*w)[128],
                                      int rg, int cA, int cB, int tid) {
  for (int kk = 0; kk < 8; kk++) {
    stage2048(&w[0][0], B + kk * 2048, tid);
    __syncthreads();
    mm_chunk16(acc, src, stride, kk * 16, w, rg, cA, cB);
    __syncthreads();
  }
}

__global__ __launch_bounds__(256, 3) void k_main(
    const float* __restrict__ Y, const float* __restrict__ A, const float* __restrict__ bfv,
    const float* __restrict__ lzw, const float* __restrict__ lrw, const float* __restrict__ lhw,
    const float* __restrict__ a1w, const float* __restrict__ a1b,
    const float* __restrict__ a2w, const float* __restrict__ a2b,
    const float* __restrict__ ow, const float* __restrict__ ob,
    float* __restrict__ out) {
  __shared__ float h_lds[64][132];   // holds h, then u=h*r, then h_new (in-place reuse)
  __shared__ float y_lds[64][20];    // padded: rows 80 words apart -> banks b/b+16
  __shared__ float w_lds[16][128];
  const int tid = threadIdx.x;
  const int cg = tid & 15, rg = tid >> 4;
  const int cA = cg * 4, cB = 64 + cg * 4;
  const int base = blockIdx.x * 64;

#pragma unroll
  for (int i = 0; i < 4; i++) {
    *(float4*)&h_lds[rg * 4 + i][cA] = make_float4(0.f, 0.f, 0.f, 0.f);
    *(float4*)&h_lds[rg * 4 + i][cB] = make_float4(0.f, 0.f, 0.f, 0.f);
  }

  float bz[8], brr[8], bh[8], ab1[8], a2r[8];
#pragma unroll
  for (int j = 0; j < 8; j++) {
    int col = (j < 4) ? (cA + j) : (cB + j - 4);
    bz[j] = bfv[col];
    brr[j] = bfv[128 + col];
    bh[j] = bfv[256 + col];
    ab1[j] = a1b[col];
    a2r[j] = a2w[col];
  }
  float b2 = a2b[0];

  float ctx[4][8], mrun[4], srun[4];
#pragma unroll
  for (int i = 0; i < 4; i++) {
    mrun[i] = -1e30f;
    srun[i] = 0.f;
#pragma unroll
    for (int j = 0; j < 8; j++) ctx[i][j] = 0.f;
  }
  __syncthreads();

  for (int t = 0; t < TT; t++) {
    {  // stage Y_t (coalesced float4 from global)
      int row = tid >> 2, f4 = tid & 3;
      int gr = base + row;
      float4 v = make_float4(0.f, 0.f, 0.f, 0.f);
      if (gr < NN) v = *(const float4*)&Y[((size_t)t * NN + gr) * 16 + f4 * 4];
      *(float4*)&y_lds[row][f4 * 4] = v;
    }
    __syncthreads();

    float accz[4][8], accr[4][8];
#pragma unroll
    for (int i = 0; i < 4; i++)
#pragma unroll
      for (int j = 0; j < 8; j++) { accz[i][j] = bz[j]; accr[i][j] = brr[j]; }

    mm16(accz, &y_lds[0][0], A, w_lds, rg, cA, cB, tid);
    mm128(accz, &h_lds[0][0], 132, lzw + HH * HH, w_lds, rg, cA, cB, tid);
    mm16(accr, &y_lds[0][0], A + 2048, w_lds, rg, cA, cB, tid);
    mm128(accr, &h_lds[0][0], 132, lrw + HH * HH, w_lds, rg, cA, cB, tid);
    // after mm128's trailing barrier, all reads of old h are done

    float z[4][8], ho[4][8];
#pragma unroll
    for (int i = 0; i < 4; i++) {
      float4 h0 = *(const float4*)&h_lds[rg * 4 + i][cA];
      float4 h1 = *(const float4*)&h_lds[rg * 4 + i][cB];
      ho[i][0] = h0.x; ho[i][1] = h0.y; ho[i][2] = h0.z; ho[i][3] = h0.w;
      ho[i][4] = h1.x; ho[i][5] = h1.y; ho[i][6] = h1.z; ho[i][7] = h1.w;
      float u[8];
#pragma unroll
      for (int j = 0; j < 8; j++) {
        z[i][j] = 1.f / (1.f + __expf(-accz[i][j]));
        float rr = 1.f / (1.f + __expf(-accr[i][j]));
        u[j] = ho[i][j] * rr;
      }
      // overwrite own cells with u = h*r (each cell has a unique owner thread)
      *(float4*)&h_lds[rg * 4 + i][cA] = make_float4(u[0], u[1], u[2], u[3]);
      *(float4*)&h_lds[rg * 4 + i][cB] = make_float4(u[4], u[5], u[6], u[7]);
    }
    // visibility of u is guaranteed by the staging barrier inside mm16/mm128 below

    float acch[4][8];
#pragma unroll
    for (int i = 0; i < 4; i++)
#pragma unroll
      for (int j = 0; j < 8; j++) acch[i][j] = bh[j];
    mm16(acch, &y_lds[0][0], A + 4096, w_lds, rg, cA, cB, tid);
    mm128(acch, &h_lds[0][0], 132, lhw + HH * HH, w_lds, rg, cA, cB, tid);
    // trailing barrier: all reads of u done -> safe to overwrite with h_new

    float hn[4][8];
#pragma unroll
    for (int i = 0; i < 4; i++) {
#pragma unroll
      for (int j = 0; j < 8; j++) {
        float th = 2.f / (1.f + __expf(-2.f * acch[i][j])) - 1.f;
        hn[i][j] = z[i][j] * ho[i][j] + (1.f - z[i][j]) * th;
      }
      *(float4*)&h_lds[rg * 4 + i][cA] = make_float4(hn[i][0], hn[i][1], hn[i][2], hn[i][3]);
      *(float4*)&h_lds[rg * 4 + i][cB] = make_float4(hn[i][4], hn[i][5], hn[i][6], hn[i][7]);
    }

    float accg[4][8];
#pragma unroll
    for (int i = 0; i < 4; i++)
#pragma unroll
      for (int j = 0; j < 8; j++) accg[i][j] = ab1[j];
    mm128(accg, &h_lds[0][0], 132, a1w, w_lds, rg, cA, cB, tid);

#pragma unroll
    for (int i = 0; i < 4; i++) {
      float p = 0.f;
#pragma unroll
      for (int j = 0; j < 8; j++) p = fmaf(fmaxf(accg[i][j], 0.f), a2r[j], p);
      p += __shfl_xor(p, 1, 64);
      p += __shfl_xor(p, 2, 64);
      p += __shfl_xor(p, 4, 64);
      p += __shfl_xor(p, 8, 64);
      float e = p + b2;
      float mn = fmaxf(mrun[i], e);
      float al = __expf(mrun[i] - mn);
      float be = __expf(e - mn);
      srun[i] = srun[i] * al + be;
      mrun[i] = mn;
#pragma unroll
      for (int j = 0; j < 8; j++) ctx[i][j] = ctx[i][j] * al + be * hn[i][j];
    }
  }

  // epilogue: out = (ctx/s) @ out_w + out_b
  stage2048(&w_lds[0][0], ow, tid);
  __syncthreads();
  float po[4][16];
#pragma unroll
  for (int i = 0; i < 4; i++) {
    float inv = 1.f / srun[i];
#pragma unroll
    for (int o = 0; o < 16; o++) po[i][o] = 0.f;
#pragma unroll
    for (int j = 0; j < 8; j++) {
      int col = (j < 4) ? (cA + j) : (cB + j - 4);
      float c = ctx[i][j] * inv;
      const float* wr = &w_lds[0][0] + col * 16;
#pragma unroll
      for (int o = 0; o < 16; o++) po[i][o] = fmaf(c, wr[o], po[i][o]);
    }
  }
#pragma unroll
  for (int mask = 1; mask < 16; mask <<= 1)
#pragma unroll
    for (int i = 0; i < 4; i++)
#pragma unroll
      for (int o = 0; o < 16; o++) po[i][o] += __shfl_xor(po[i][o], mask, 64);
  float obv = ob[cg];
#pragma unroll
  for (int i = 0; i < 4; i++) {
    int gr = base + rg * 4 + i;
    if (gr < NN) out[gr * 16 + cg] = po[i][cg] + obv;
  }
}

extern "C" void kernel_launch(void* const* d_in, const int* in_sizes, int n_in,
                              void* d_out, int out_size, void* d_ws, size_t ws_size,
                              hipStream_t stream) {
  const float* x   = (const float*)d_in[0];
  const int*   ei  = (const int*)d_in[1];
  const float* ew  = (const float*)d_in[2];
  const float* czw = (const float*)d_in[3],  *czb = (const float*)d_in[4];
  const float* crw = (const float*)d_in[5],  *crb = (const float*)d_in[6];
  const float* chw = (const float*)d_in[7],  *chb = (const float*)d_in[8];
  const float* lzw = (const float*)d_in[9],  *lzb = (const float*)d_in[10];
  const float* lrw = (const float*)d_in[11], *lrb = (const float*)d_in[12];
  const float* lhw = (const float*)d_in[13], *lhb = (const float*)d_in[14];
  const float* a1w = (const float*)d_in[15], *a1b = (const float*)d_in[16];
  const float* a2w = (const float*)d_in[17], *a2b = (const float*)d_in[18];
  const float* ow  = (const float*)d_in[19], *ob  = (const float*)d_in[20];

  float* ws  = (float*)d_ws;
  float* deg = ws;            // N (becomes dinv)
  float* A   = ws + 50048;    // 3*16*128 fused conv@lin_top
  float* bfv = ws + 56192;    // 3*128 fused biases
  float* Y   = ws + 56576;    // [T][N][16] propagated features
  float* out = (float*)d_out;

  hipMemsetAsync(deg, 0, NN * sizeof(float), stream);
  k_deg<<<(EE + 255) / 256, 256, 0, stream>>>(ei, ew, deg);
  k_dinv<<<(NN + 255) / 256, 256, 0, stream>>>(deg);
  k_inity<<<(TT * NN * 4 + 255) / 256, 256, 0, stream>>>(x, deg, Y);
  k_edges<<<(EE * 64) / 256, 256, 0, stream>>>(ei, ew, deg, x, Y);
  k_prep<<<3, 256, 0, stream>>>(czw, czb, lzw, lzb, crw, crb, lrw, lrb,
                                chw, chb, lhw, lhb, A, bfv);
  k_main<<<(NN + 63) / 64, 256, 0, stream>>>(Y, A, bfv, lzw, lrw, lhw,
                                             a1w, a1b, a2w, a2b, ow, ob, out);
}

// Round 3
// 880.378 us; speedup vs baseline: 4.1401x; 4.1401x over previous
//
#include <hip/hip_runtime.h>
#include <cstddef>

#define NN 50000
#define TT 12
#define HH 128
#define EE 800000

typedef short v8s __attribute__((ext_vector_type(8)));
typedef float v4f __attribute__((ext_vector_type(4)));
#define MFMA(a, b, c) __builtin_amdgcn_mfma_f32_16x16x32_bf16(a, b, c, 0, 0, 0)

__device__ __forceinline__ unsigned short f2bf(float f) {
  unsigned int u = __float_as_uint(f);
  u += 0x7FFF + ((u >> 16) & 1);
  return (unsigned short)(u >> 16);
}
__device__ __forceinline__ float bf2f(unsigned short b) {
  return __uint_as_float(((unsigned int)b) << 16);
}

// ---------------- degree / normalization ----------------
__global__ void k_deg(const int* __restrict__ ei, const float* __restrict__ ew,
                      float* __restrict__ deg) {
  int e = blockIdx.x * 256 + threadIdx.x;
  if (e < EE) atomicAdd(&deg[ei[EE + e]], ew[e]);
}

__global__ void k_dinv(float* __restrict__ deg) {
  int n = blockIdx.x * 256 + threadIdx.x;
  if (n < NN) deg[n] = rsqrtf(deg[n] + 1.0f);  // self-loop weight 1 included
}

// ---------------- CSR build ----------------
__global__ void k_count(const int* __restrict__ ei, int* __restrict__ cnt) {
  int e = blockIdx.x * 256 + threadIdx.x;
  if (e < EE) atomicAdd(&cnt[ei[EE + e]], 1);
}

__global__ void k_scan(const int* __restrict__ cnt, int* __restrict__ row) {
  __shared__ int ps[1024];
  int tid = threadIdx.x;
  const int CH = 49;  // 1024*49 >= NN
  int b0 = tid * CH;
  int s = 0;
  for (int i = 0; i < CH; i++) { int idx = b0 + i; if (idx < NN) s += cnt[idx]; }
  ps[tid] = s;
  __syncthreads();
  for (int off = 1; off < 1024; off <<= 1) {
    int v = (tid >= off) ? ps[tid - off] : 0;
    __syncthreads();
    ps[tid] += v;
    __syncthreads();
  }
  int bb = (tid > 0) ? ps[tid - 1] : 0;
  for (int i = 0; i < CH; i++) {
    int idx = b0 + i;
    if (idx < NN) { row[idx] = bb; bb += cnt[idx]; }
  }
  if (tid == 1023) row[NN] = bb;
}

__global__ void k_scatter(const int* __restrict__ ei, const float* __restrict__ ew,
                          const float* __restrict__ dinv, const int* __restrict__ row,
                          int* __restrict__ cur, int* __restrict__ csr_s,
                          float* __restrict__ csr_w) {
  int e = blockIdx.x * 256 + threadIdx.x;
  if (e >= EE) return;
  int s = ei[e], d = ei[EE + e];
  int pos = row[d] + atomicAdd(&cur[d], 1);
  csr_s[pos] = s;
  csr_w[pos] = dinv[s] * ew[e] * dinv[d];
}

// one wave per dst node; lane covers 3 of the 192 (f,t) columns
__global__ void k_gather(const int* __restrict__ row, const int* __restrict__ csr_s,
                         const float* __restrict__ csr_w, const float* __restrict__ dinv,
                         const float* __restrict__ x, unsigned short* __restrict__ Ybf) {
  int d = blockIdx.x * 4 + (threadIdx.x >> 6);
  if (d >= NN) return;
  int lane = threadIdx.x & 63;
  float acc0, acc1, acc2;
  {
    float dv = dinv[d]; dv *= dv;  // self loop
    const float* xr = x + (size_t)d * 192;
    acc0 = dv * xr[lane]; acc1 = dv * xr[lane + 64]; acc2 = dv * xr[lane + 128];
  }
  int kb = row[d], ke = row[d + 1];
  for (int k = kb; k < ke; k++) {
    int s = csr_s[k];
    float wv = csr_w[k];
    const float* xr = x + (size_t)s * 192;
    acc0 = fmaf(wv, xr[lane], acc0);
    acc1 = fmaf(wv, xr[lane + 64], acc1);
    acc2 = fmaf(wv, xr[lane + 128], acc2);
  }
  int c, t, f;
  c = lane;       t = c % TT; f = c / TT; Ybf[((size_t)t * NN + d) * 16 + f] = f2bf(acc0);
  c = lane + 64;  t = c % TT; f = c / TT; Ybf[((size_t)t * NN + d) * 16 + f] = f2bf(acc1);
  c = lane + 128; t = c % TT; f = c / TT; Ybf[((size_t)t * NN + d) * 16 + f] = f2bf(acc2);
}

// ---------------- fused weight prep: A = conv_w @ lin_top, bfv = conv_b @ lin_top + lin_b
__global__ void k_prep(const float* __restrict__ czw, const float* __restrict__ czb,
                       const float* __restrict__ lzw, const float* __restrict__ lzb,
                       const float* __restrict__ crw, const float* __restrict__ crb,
                       const float* __restrict__ lrw, const float* __restrict__ lrb,
                       const float* __restrict__ chw, const float* __restrict__ chb,
                       const float* __restrict__ lhw, const float* __restrict__ lhb,
                       float* __restrict__ A, float* __restrict__ bfv) {
  const float *cw, *cb, *lw, *lb;
  if (blockIdx.x == 0)      { cw = czw; cb = czb; lw = lzw; lb = lzb; }
  else if (blockIdx.x == 1) { cw = crw; cb = crb; lw = lrw; lb = lrb; }
  else                      { cw = chw; cb = chb; lw = lhw; lb = lhb; }
  float* Ao = A + blockIdx.x * 2048;
  float* bo = bfv + blockIdx.x * 128;
  for (int idx = threadIdx.x; idx < 2048; idx += 256) {
    int f = idx >> 7, j = idx & 127;
    float acc = 0.f;
    for (int k = 0; k < 128; k++) acc = fmaf(cw[f * 128 + k], lw[k * 128 + j], acc);
    Ao[idx] = acc;
  }
  for (int j = threadIdx.x; j < 128; j += 256) {
    float acc = lb[j];
    for (int k = 0; k < 128; k++) acc = fmaf(cb[k], lw[k * 128 + j], acc);
    bo[j] = acc;
  }
}

// ---------------- main fused GRU + attention + output (MFMA, bf16x3 fp32-emu) ----
// 8 waves, 64 rows/block. Computes D^T = W^T h^T: wave w owns weight cols
// 16w..16w+15 as persistent A-frags (hi/lo split). h in LDS as split bf16.
// C layout (m89): col=lane&15 -> node n offset; row=(lane>>4)*4+reg -> weight col.
__global__ __launch_bounds__(512, 2) void k_main(
    const unsigned short* __restrict__ Ybf, const float* __restrict__ A,
    const float* __restrict__ bfv,
    const float* __restrict__ lzw, const float* __restrict__ lrw, const float* __restrict__ lhw,
    const float* __restrict__ a1w, const float* __restrict__ a1b,
    const float* __restrict__ a2w, const float* __restrict__ a2b,
    const float* __restrict__ ow, const float* __restrict__ ob,
    float* __restrict__ out) {
  const int HS = 136, YS = 40;
  __shared__ unsigned short h_hi[64 * 136];
  __shared__ unsigned short h_lo[64 * 136];
  __shared__ unsigned short y_bf[64 * 40];
  __shared__ float sc[64 * 9];
  __shared__ float ctxb[64 * 136];
  __shared__ float owb[2048];

  const int tid = threadIdx.x;
  const int w = tid >> 6;
  const int lane = tid & 63;
  const int ln = lane & 15;
  const int lg = lane >> 4;
  const int kg = 8 * lg;
  const int cw = 16 * w + ln;      // weight column (A-operand row)
  const int co = 16 * w + 4 * lg;  // own C-cell column base
  const int base = blockIdx.x * 64;

  for (int i = tid; i < 64 * 136; i += 512) { h_hi[i] = 0; h_lo[i] = 0; }
  for (int i = tid; i < 64 * 40; i += 512) y_bf[i] = 0;

  // persistent weight fragments (split bf16)
  v8s whZ[4], wlZ[4], whR[4], wlR[4], whH[4], wlH[4], waA[4];
  v8s afZ, afR, afH;
#pragma unroll
  for (int ks = 0; ks < 4; ks++) {
#pragma unroll
    for (int j = 0; j < 8; j++) {
      int krow = 128 + 32 * ks + kg + j;  // h-part rows of lin weights
      float vz = lzw[krow * HH + cw];
      float vr = lrw[krow * HH + cw];
      float vh = lhw[krow * HH + cw];
      float va = a1w[(32 * ks + kg + j) * HH + cw];
      unsigned short hb;
      hb = f2bf(vz); whZ[ks][j] = (short)hb; wlZ[ks][j] = (short)f2bf(vz - bf2f(hb));
      hb = f2bf(vr); whR[ks][j] = (short)hb; wlR[ks][j] = (short)f2bf(vr - bf2f(hb));
      hb = f2bf(vh); whH[ks][j] = (short)hb; wlH[ks][j] = (short)f2bf(vh - bf2f(hb));
      waA[ks][j] = (short)f2bf(va);
    }
  }
#pragma unroll
  for (int j = 0; j < 8; j++) {
    int f = (kg + j) & 15;
    afZ[j] = (lg < 2) ? (short)f2bf(A[f * HH + cw]) : (short)0;
    afR[j] = (lg < 2) ? (short)f2bf(A[2048 + f * HH + cw]) : (short)0;
    afH[j] = (lg < 2) ? (short)f2bf(A[4096 + f * HH + cw]) : (short)0;
  }

  const float4 bz4 = *(const float4*)&bfv[co];
  const float4 br4 = *(const float4*)&bfv[128 + co];
  const float4 bh4 = *(const float4*)&bfv[256 + co];
  const float4 ab4 = *(const float4*)&a1b[co];
  const float4 a2v = *(const float4*)&a2w[co];
  const float b2 = a2b[0];

  v4f ctx[4];
  float mrun[4], srun[4];
#pragma unroll
  for (int nt = 0; nt < 4; nt++) {
    ctx[nt] = (v4f){0.f, 0.f, 0.f, 0.f};
    mrun[nt] = -1e30f; srun[nt] = 0.f;
  }
  __syncthreads();

  for (int t = 0; t < TT; t++) {
    {  // stage Y_t (already bf16; coalesced uint copies)
      int rw = tid >> 3, fp = (tid & 7) * 2;
      int gr = base + rw;
      unsigned int v = 0;
      if (gr < NN) v = *(const unsigned int*)&Ybf[((size_t)t * NN + gr) * 16 + fp];
      *(unsigned int*)&y_bf[rw * YS + fp] = v;
    }
    __syncthreads();

    // ---- phase A: z and r gates ----
    v4f az[4], ar[4];
#pragma unroll
    for (int nt = 0; nt < 4; nt++) {
      const int hb = (16 * nt + ln) * HS;
      v8s yf = *(const v8s*)&y_bf[(16 * nt + ln) * YS + kg];
      v4f z0 = (v4f){bz4.x, bz4.y, bz4.z, bz4.w};
      v4f r0 = (v4f){br4.x, br4.y, br4.z, br4.w};
      z0 = MFMA(afZ, yf, z0);
      r0 = MFMA(afR, yf, r0);
#pragma unroll
      for (int ks = 0; ks < 4; ks++) {
        v8s hf = *(const v8s*)&h_hi[hb + 32 * ks + kg];
        z0 = MFMA(whZ[ks], hf, z0); z0 = MFMA(wlZ[ks], hf, z0);
        r0 = MFMA(whR[ks], hf, r0); r0 = MFMA(wlR[ks], hf, r0);
      }
#pragma unroll
      for (int ks = 0; ks < 4; ks++) {
        v8s lf = *(const v8s*)&h_lo[hb + 32 * ks + kg];
        z0 = MFMA(whZ[ks], lf, z0);
        r0 = MFMA(whR[ks], lf, r0);
      }
      az[nt] = z0; ar[nt] = r0;
    }
    __syncthreads();  // all h reads done

    // ---- phase B: sigmoids, u = h*r (overwrite own h cells) ----
    v4f zf[4], ho[4];
#pragma unroll
    for (int nt = 0; nt < 4; nt++) {
      const int idx = (16 * nt + ln) * HS + co;
      ushort4 h4 = *(const ushort4*)&h_hi[idx];
      ushort4 l4 = *(const ushort4*)&h_lo[idx];
      float hov0 = bf2f(h4.x) + bf2f(l4.x), hov1 = bf2f(h4.y) + bf2f(l4.y);
      float hov2 = bf2f(h4.z) + bf2f(l4.z), hov3 = bf2f(h4.w) + bf2f(l4.w);
      float zz0 = 1.f / (1.f + __expf(-az[nt][0]));
      float zz1 = 1.f / (1.f + __expf(-az[nt][1]));
      float zz2 = 1.f / (1.f + __expf(-az[nt][2]));
      float zz3 = 1.f / (1.f + __expf(-az[nt][3]));
      float u0 = hov0 / (1.f + __expf(-ar[nt][0]));
      float u1 = hov1 / (1.f + __expf(-ar[nt][1]));
      float u2 = hov2 / (1.f + __expf(-ar[nt][2]));
      float u3 = hov3 / (1.f + __expf(-ar[nt][3]));
      ushort4 uh, ul;
      uh.x = f2bf(u0); ul.x = f2bf(u0 - bf2f(uh.x));
      uh.y = f2bf(u1); ul.y = f2bf(u1 - bf2f(uh.y));
      uh.z = f2bf(u2); ul.z = f2bf(u2 - bf2f(uh.z));
      uh.w = f2bf(u3); ul.w = f2bf(u3 - bf2f(uh.w));
      *(ushort4*)&h_hi[idx] = uh;
      *(ushort4*)&h_lo[idx] = ul;
      zf[nt] = (v4f){zz0, zz1, zz2, zz3};
      ho[nt] = (v4f){hov0, hov1, hov2, hov3};
    }
    __syncthreads();  // u visible

    // ---- phase C: candidate gate ----
    v4f hn[4];
#pragma unroll
    for (int nt = 0; nt < 4; nt++) {
      const int hb = (16 * nt + ln) * HS;
      v8s yf = *(const v8s*)&y_bf[(16 * nt + ln) * YS + kg];
      v4f hh = (v4f){bh4.x, bh4.y, bh4.z, bh4.w};
      hh = MFMA(afH, yf, hh);
#pragma unroll
      for (int ks = 0; ks < 4; ks++) {
        v8s uf = *(const v8s*)&h_hi[hb + 32 * ks + kg];
        hh = MFMA(whH[ks], uf, hh); hh = MFMA(wlH[ks], uf, hh);
      }
#pragma unroll
      for (int ks = 0; ks < 4; ks++) {
        v8s lf = *(const v8s*)&h_lo[hb + 32 * ks + kg];
        hh = MFMA(whH[ks], lf, hh);
      }
      v4f o;
#pragma unroll
      for (int r = 0; r < 4; r++) {
        float th = 2.f / (1.f + __expf(-2.f * hh[r])) - 1.f;
        o[r] = zf[nt][r] * ho[nt][r] + (1.f - zf[nt][r]) * th;
      }
      hn[nt] = o;
    }
    __syncthreads();  // all u reads done

#pragma unroll
    for (int nt = 0; nt < 4; nt++) {  // write h_new (own cells)
      const int idx = (16 * nt + ln) * HS + co;
      ushort4 nh, nl;
      nh.x = f2bf(hn[nt][0]); nl.x = f2bf(hn[nt][0] - bf2f(nh.x));
      nh.y = f2bf(hn[nt][1]); nl.y = f2bf(hn[nt][1] - bf2f(nh.y));
      nh.z = f2bf(hn[nt][2]); nl.z = f2bf(hn[nt][2] - bf2f(nh.z));
      nh.w = f2bf(hn[nt][3]); nl.w = f2bf(hn[nt][3] - bf2f(nh.w));
      *(ushort4*)&h_hi[idx] = nh;
      *(ushort4*)&h_lo[idx] = nl;
    }
    __syncthreads();  // h_new visible

    // ---- phase D: attention score + online softmax ----
    float p[4];
#pragma unroll
    for (int nt = 0; nt < 4; nt++) {
      const int hb = (16 * nt + ln) * HS;
      v4f g0 = (v4f){ab4.x, ab4.y, ab4.z, ab4.w};
#pragma unroll
      for (int ks = 0; ks < 4; ks++) {
        v8s hf = *(const v8s*)&h_hi[hb + 32 * ks + kg];
        g0 = MFMA(waA[ks], hf, g0);
      }
#pragma unroll
      for (int ks = 0; ks < 4; ks++) {
        v8s lf = *(const v8s*)&h_lo[hb + 32 * ks + kg];
        g0 = MFMA(waA[ks], lf, g0);
      }
      p[nt] = fmaxf(g0[0], 0.f) * a2v.x + fmaxf(g0[1], 0.f) * a2v.y +
              fmaxf(g0[2], 0.f) * a2v.z + fmaxf(g0[3], 0.f) * a2v.w;
      p[nt] += __shfl_xor(p[nt], 16, 64);
      p[nt] += __shfl_xor(p[nt], 32, 64);
    }
    if (lane < 16) {
#pragma unroll
      for (int nt = 0; nt < 4; nt++) sc[(16 * nt + lane) * 9 + w] = p[nt];
    }
    __syncthreads();
#pragma unroll
    for (int nt = 0; nt < 4; nt++) {
      const float* sr = &sc[(16 * nt + ln) * 9];
      float e = b2 + sr[0] + sr[1] + sr[2] + sr[3] + sr[4] + sr[5] + sr[6] + sr[7];
      float mn = fmaxf(mrun[nt], e);
      float al = __expf(mrun[nt] - mn);
      float be = __expf(e - mn);
      srun[nt] = srun[nt] * al + be;
      mrun[nt] = mn;
#pragma unroll
      for (int r = 0; r < 4; r++) ctx[nt][r] = ctx[nt][r] * al + be * hn[nt][r];
    }
  }

  // ---- epilogue: out = (ctx/s) @ out_w + out_b ----
#pragma unroll
  for (int nt = 0; nt < 4; nt++) {
    float inv = 1.f / srun[nt];
    *(float4*)&ctxb[(16 * nt + ln) * 136 + co] =
        make_float4(ctx[nt][0] * inv, ctx[nt][1] * inv, ctx[nt][2] * inv, ctx[nt][3] * inv);
  }
  for (int i = tid; i < 2048; i += 512) owb[i] = ow[i];
  __syncthreads();
#pragma unroll
  for (int pp = 0; pp < 2; pp++) {
    int idx = tid + pp * 512;
    int n = idx >> 4, o = idx & 15;
    float acc = ob[o];
    const float* cr = &ctxb[n * 136];
#pragma unroll 8
    for (int c = 0; c < 128; c++) acc = fmaf(cr[c], owb[c * 16 + o], acc);
    int gn = base + n;
    if (gn < NN) out[gn * 16 + o] = acc;
  }
}

extern "C" void kernel_launch(void* const* d_in, const int* in_sizes, int n_in,
                              void* d_out, int out_size, void* d_ws, size_t ws_size,
                              hipStream_t stream) {
  const float* x   = (const float*)d_in[0];
  const int*   ei  = (const int*)d_in[1];
  const float* ew  = (const float*)d_in[2];
  const float* czw = (const float*)d_in[3],  *czb = (const float*)d_in[4];
  const float* crw = (const float*)d_in[5],  *crb = (const float*)d_in[6];
  const float* chw = (const float*)d_in[7],  *chb = (const float*)d_in[8];
  const float* lzw = (const float*)d_in[9],  *lzb = (const float*)d_in[10];
  const float* lrw = (const float*)d_in[11], *lrb = (const float*)d_in[12];
  const float* lhw = (const float*)d_in[13], *lhb = (const float*)d_in[14];
  const float* a1w = (const float*)d_in[15], *a1b = (const float*)d_in[16];
  const float* a2w = (const float*)d_in[17], *a2b = (const float*)d_in[18];
  const float* ow  = (const float*)d_in[19], *ob  = (const float*)d_in[20];

  float* ws = (float*)d_ws;
  float* deg   = ws;                       // N f32 (becomes dinv)
  int*   cnt   = (int*)(ws + 50048);       // N int (histogram, then cursor)
  int*   row   = (int*)(ws + 100096);      // N+1 int
  int*   csr_s = (int*)(ws + 150400);      // E int
  float* csr_w = ws + 950400;              // E f32
  float* A     = ws + 1750400;             // 3*16*128
  float* bfv   = ws + 1756544;             // 3*128
  unsigned short* Ybf = (unsigned short*)(ws + 1756928);  // [T][N][16] bf16
  float* out = (float*)d_out;

  hipMemsetAsync(ws, 0, 100096 * sizeof(float), stream);  // deg + cnt
  k_deg<<<3125, 256, 0, stream>>>(ei, ew, deg);
  k_count<<<3125, 256, 0, stream>>>(ei, cnt);
  k_dinv<<<196, 256, 0, stream>>>(deg);
  k_scan<<<1, 1024, 0, stream>>>(cnt, row);
  hipMemsetAsync(cnt, 0, 50000 * sizeof(int), stream);
  k_scatter<<<3125, 256, 0, stream>>>(ei, ew, deg, row, cnt, csr_s, csr_w);
  k_gather<<<12500, 256, 0, stream>>>(row, csr_s, csr_w, deg, x, Ybf);
  k_prep<<<3, 256, 0, stream>>>(czw, czb, lzw, lzb, crw, crb, lrw, lrb,
                                chw, chb, lhw, lhb, A, bfv);
  k_main<<<782, 512, 0, stream>>>(Ybf, A, bfv, lzw, lrw, lhw,
                                  a1w, a1b, a2w, a2b, ow, ob, out);
}